// Round 7
// baseline (429.270 us; speedup 1.0000x reference)
//
#include <hip/hip_runtime.h>
#include <hip/hip_bf16.h>
#include <hip/hip_cooperative_groups.h>

namespace cg = cooperative_groups;

// ---------------------------------------------------------------------------
// Single cooperative mega-kernel. Grid 256 x 512. Phases separated by
// grid.sync(); all inter-phase data through d_ws globals.
// ---------------------------------------------------------------------------
__global__ __launch_bounds__(512) void mega_k(
    const int* __restrict__ inp, const float* __restrict__ emb,
    const float* __restrict__ Wp, const float* __restrict__ bp,
    const float* __restrict__ Wo, const float* __restrict__ bo,
    const float* __restrict__ ln1_g, const float* __restrict__ ln1_b,
    const float* __restrict__ W1, const float* __restrict__ b1,
    const float* __restrict__ W2, const float* __restrict__ b2,
    const float* __restrict__ ln2_g, const float* __restrict__ ln2_b,
    const float* __restrict__ Wh, const float* __restrict__ bh,
    const float* __restrict__ Wf, const float* __restrict__ bf,
    float* __restrict__ out,
    float* __restrict__ PE, float* __restrict__ X0, float* __restrict__ r,
    float* __restrict__ alpha, float* __restrict__ C0, float* __restrict__ Y1,
    float* __restrict__ Tpp, float* __restrict__ Gp, float* __restrict__ Hp2p,
    float* __restrict__ Pl)
{
    cg::grid_group grid = cg::this_grid();
    __shared__ __align__(16) float smem[10400];
    int bid = blockIdx.x, t = threadIdx.x;

    // ============ P1: qr (blocks 0-127)  ||  PE table (blocks 128-255) =====
    if (bid < 128) {
        int b = bid >> 2, h = bid & 3;
        float* xs  = smem;            // 512
        float* red = smem + 512;      // 512
        float* q0s = smem + 1024;     // 128
        int tok0 = inp[b * 1024];
        // PE row s=0: sin(0)=0 (even d), cos(0)=1 (odd d)
        float xv = emb[(long)tok0 * 512 + t] + ((t & 1) ? 1.0f : 0.0f);
        xs[t] = xv;
        if (h == 0) X0[b * 512 + t] = xv;
        __syncthreads();
        int f = t & 127, q = t >> 7;
        const float* wq = Wp + (long)h * 196608 + f;
        float acc = 0.f;
#pragma unroll 8
        for (int d = q * 128; d < q * 128 + 128; d++)
            acc += xs[d] * wq[(long)d * 384];
        red[t] = acc;
        __syncthreads();
        if (t < 128)
            q0s[t] = red[t] + red[t + 128] + red[t + 256] + red[t + 384]
                   + bp[h * 384 + t];
        __syncthreads();
        if (t < 128) red[t] = q0s[t] * bp[h * 384 + 128 + t];
        __syncthreads();
        for (int w = 64; w >= 1; w >>= 1) {
            if (t < w) red[t] += red[t + w];
            __syncthreads();
        }
        if (t == 0) alpha[b * 4 + h] = red[0];
        const float4* q4 = (const float4*)q0s;
        const float4* wr = (const float4*)(Wp + (long)h * 196608 + (long)t * 384 + 128);
        float a2 = 0.f;
#pragma unroll 8
        for (int f4 = 0; f4 < 32; f4++) {
            float4 w = wr[f4], qq = q4[f4];
            a2 += w.x * qq.x + w.y * qq.y + w.z * qq.z + w.w * qq.w;
        }
        r[((long)(b * 4 + h)) * 512 + t] = a2;
    } else {
        int base = (bid - 128) * 512 + t;
#pragma unroll
        for (int i = 0; i < 8; i++) {
            int idx = base + i * 65536;      // < 524288
            int d = idx & 511, s = idx >> 9;
            float expo = (float)(d & ~1) * (1.0f / 512.0f);
            float ang = (float)s * exp2f(-expo * 13.287712379549449f);
            PE[idx] = (d & 1) ? cosf(ang) : sinf(ang);
        }
    }
    grid.sync();

    // ============ P2: fused x-gather -> u -> t' partials (all 256 blocks) ==
    {
        int b = bid >> 3, g8 = bid & 7;
        float* xs   = smem;                    // 16*516 = 8256
        float* rs   = smem + 8256;             // 2048
        float* us   = smem + 10304;            // 64
        int*   toks = (int*)(smem + 10368);    // 16
        ((float4*)rs)[t] = ((const float4*)(r + (long)b * 2048))[t];
        int uh = (t >> 3) & 3;
        float alph = alpha[b * 4 + uh];
        float accT[4] = {0.f, 0.f, 0.f, 0.f};
        float gacc = 0.f;
        for (int it = 0; it < 8; it++) {
            int s0 = (g8 * 8 + it) * 16;
            __syncthreads();                    // protect xs/us from prev readers
            if (t < 16) toks[t] = inp[b * 1024 + s0 + t];
            __syncthreads();
            {   // stage 16 rows of x = emb[tok] + PE[s]
                int row = t >> 5, seg = t & 31;
                int tok = toks[row];
                const float4* e  = (const float4*)&emb[(long)tok * 512 + seg * 16];
                const float4* pp = (const float4*)&PE[(long)(s0 + row) * 512 + seg * 16];
                float* xrow = &xs[row * 516 + seg * 16];
#pragma unroll
                for (int k = 0; k < 4; k++) {
                    float4 ev = e[k], pv = pp[k];
                    *(float4*)&xrow[k * 4] = make_float4(ev.x + pv.x, ev.y + pv.y,
                                                         ev.z + pv.z, ev.w + pv.w);
                }
            }
            __syncthreads();
            {   // u[s,h]: t = s*32 + h*8 + e8; interleaved dot (bank-conflict-free)
                int s = t >> 5, e8 = t & 7;
                const float* xrow = xs + s * 516 + e8 * 4;
                const float* rrow = rs + uh * 512 + e8 * 4;
                float acc = 0.f;
#pragma unroll 8
                for (int k = 0; k < 16; k++) {
                    float4 xv = *(const float4*)&xrow[k * 32];
                    float4 rv = *(const float4*)&rrow[k * 32];
                    acc += xv.x * rv.x + xv.y * rv.y + xv.z * rv.z + xv.w * rv.w;
                }
                acc += __shfl_xor(acc, 1);
                acc += __shfl_xor(acc, 2);
                acc += __shfl_xor(acc, 4);
                if (e8 == 0) us[s * 4 + uh] = acc + alph;
            }
            __syncthreads();
            if (t < 4) {
#pragma unroll
                for (int s = 0; s < 16; s++) gacc += us[s * 4 + t];
            }
#pragma unroll 4
            for (int s = 0; s < 16; s++) {      // t' accumulate, d = t
                float x = xs[s * 516 + t];
                accT[0] += us[s * 4 + 0] * x;
                accT[1] += us[s * 4 + 1] * x;
                accT[2] += us[s * 4 + 2] * x;
                accT[3] += us[s * 4 + 3] * x;
            }
        }
#pragma unroll
        for (int h = 0; h < 4; h++)
            Tpp[((long)((b * 8 + g8) * 4 + h)) * 512 + t] = accT[h];
        if (t < 4) Gp[(b * 8 + g8) * 4 + t] = gacc;
    }
    grid.sync();

    // ============ P3: att1 — c0 = scale*(t'.Wv + gamma*bv)  (256 blocks) ===
    {
        int b = bid >> 3, jt = bid & 7;
        int h = jt >> 1, e0 = (jt & 1) * 64;
        float* tps = smem;            // 512
        float* red = smem + 512;      // 512
        float v = 0.f;
#pragma unroll
        for (int g = 0; g < 8; g++)
            v += Tpp[((long)((b * 8 + g) * 4 + h)) * 512 + t];
        tps[t] = v;
        __syncthreads();
        int e = e0 + (t & 63), rg = t >> 6;
        const float* wv = Wp + (long)h * 196608 + 256 + e;
        float acc = 0.f;
#pragma unroll 8
        for (int d = rg * 64; d < rg * 64 + 64; d++)
            acc += tps[d] * wv[(long)d * 384];
        red[t] = acc;
        __syncthreads();
        if (t < 64) {
            float sum = 0.f, gam = 0.f;
#pragma unroll
            for (int g = 0; g < 8; g++) sum += red[t + g * 64];
#pragma unroll
            for (int g = 0; g < 8; g++) gam += Gp[(b * 8 + g) * 4 + h];
            float c = 0.03125f * (sum + gam * bp[h * 384 + 256 + e0 + t]);
            C0[b * 512 + h * 128 + e0 + t] = c;
        }
    }
    grid.sync();

    // ============ P4: att2 + LN1  (32 blocks, one per b) ===================
    if (bid < 32) {
        int b = bid;
        float* c0s = smem;            // 512
        float* sd  = smem + 512;      // 16
        c0s[t] = C0[b * 512 + t];
        __syncthreads();
        float acc = bo[t];
#pragma unroll 8
        for (int d = 0; d < 512; d++)
            acc += c0s[d] * Wo[(long)d * 512 + t];
        float a = acc + X0[b * 512 + t];
        float s = a;
#pragma unroll
        for (int off = 32; off; off >>= 1) s += __shfl_down(s, off);
        if ((t & 63) == 0) sd[t >> 6] = s;
        __syncthreads();
        float mean = (sd[0] + sd[1] + sd[2] + sd[3] + sd[4] + sd[5] + sd[6] + sd[7])
                     * (1.0f / 512.0f);
        float d0 = a - mean;
        float vv = d0 * d0;
#pragma unroll
        for (int off = 32; off; off >>= 1) vv += __shfl_down(vv, off);
        if ((t & 63) == 0) sd[8 + (t >> 6)] = vv;
        __syncthreads();
        float var = (sd[8] + sd[9] + sd[10] + sd[11] + sd[12] + sd[13] + sd[14] + sd[15])
                    * (1.0f / 512.0f);
        float rstd = rsqrtf(var + 0.001f);
        Y1[b * 512 + t] = d0 * rstd * ln1_g[t] + ln1_b[t];
    }
    grid.sync();

    // ============ P5: fused FFN1+FFN2 partials (64 blocks x 32 H1-cols) ====
    if (bid < 64) {
        int g = bid;
        float* Y1s = smem;            // 32 x 256 = 8192 (half of K at a time)
        float* H1s = smem + 8192;     // 32 x 33 = 1056
        int c = t & 31, r2 = t >> 5;  // r2 0..15
        float acc0 = 0.f, acc1 = 0.f;
        const float* w1 = W1 + g * 32 + c;
        for (int half = 0; half < 2; half++) {
            __syncthreads();
#pragma unroll
            for (int i = 0; i < 4; i++) {
                int idx = t + i * 512;              // < 2048 float4
                int row = idx >> 6, seg = idx & 63;
                ((float4*)Y1s)[idx] =
                    *(const float4*)&Y1[(long)row * 512 + half * 256 + seg * 4];
            }
            __syncthreads();
#pragma unroll 4
            for (int k = 0; k < 256; k++) {
                float w = w1[(long)(half * 256 + k) * 2048];
                acc0 += Y1s[r2 * 256 + k] * w;
                acc1 += Y1s[(r2 + 16) * 256 + k] * w;
            }
        }
        int col = g * 32 + c;
        __syncthreads();
        H1s[r2 * 33 + c]        = fmaxf(acc0 + b1[col], 0.f);
        H1s[(r2 + 16) * 33 + c] = fmaxf(acc1 + b1[col], 0.f);
        __syncthreads();
        float accr[32];
#pragma unroll
        for (int rr = 0; rr < 32; rr++) accr[rr] = 0.f;
        const float* w2 = W2 + (long)(g * 32) * 512 + t;
#pragma unroll 4
        for (int k = 0; k < 32; k++) {
            float w = w2[(long)k * 512];
#pragma unroll
            for (int rr = 0; rr < 32; rr++)
                accr[rr] += H1s[rr * 33 + k] * w;
        }
#pragma unroll
        for (int rr = 0; rr < 32; rr++)
            Hp2p[((long)(g * 32 + rr)) * 512 + t] = accr[rr];
    }
    grid.sync();

    // ============ P6: LN2 + head partials  (256 blocks = 32b x 8jt) ========
    {
        int b = bid >> 3, jt = bid & 7;
        float* xs  = smem;            // 512
        float* red = smem + 512;      // 512
        float* sd  = smem + 1024;     // 16
        float v = b2[t] + Y1[b * 512 + t];
#pragma unroll 8
        for (int g = 0; g < 64; g++)
            v += Hp2p[((long)(g * 32 + b)) * 512 + t];
        float s = v;
#pragma unroll
        for (int off = 32; off; off >>= 1) s += __shfl_down(s, off);
        if ((t & 63) == 0) sd[t >> 6] = s;
        __syncthreads();
        float mean = (sd[0] + sd[1] + sd[2] + sd[3] + sd[4] + sd[5] + sd[6] + sd[7])
                     * (1.0f / 512.0f);
        float d0 = v - mean;
        float vv = d0 * d0;
#pragma unroll
        for (int off = 32; off; off >>= 1) vv += __shfl_down(vv, off);
        if ((t & 63) == 0) sd[8 + (t >> 6)] = vv;
        __syncthreads();
        float var = (sd[8] + sd[9] + sd[10] + sd[11] + sd[12] + sd[13] + sd[14] + sd[15])
                    * (1.0f / 512.0f);
        float rstd = rsqrtf(var + 0.001f);
        xs[t] = d0 * rstd * ln2_g[t] + ln2_b[t];
        __syncthreads();
        int j = jt * 64 + (t & 63), rg = t >> 6;
        const float* w = Wh + j;
        float acc = 0.f;
#pragma unroll 8
        for (int d = rg * 64; d < rg * 64 + 64; d++)
            acc += xs[d] * w[(long)d * 512];
        red[t] = acc;
        __syncthreads();
        if (t < 64) {
            int jj = jt * 64 + t;
            float hid = bh[jj];
#pragma unroll
            for (int g = 0; g < 8; g++) hid += red[t + g * 64];
            hid = fmaxf(hid, 0.f);
            float p = hid * Wf[jj];
#pragma unroll
            for (int off = 32; off; off >>= 1) p += __shfl_down(p, off);
            if (t == 0) Pl[b * 8 + jt] = p;
        }
    }
    grid.sync();

    // ============ P7: final ================================================
    if (bid == 0 && t < 32) {
        float logit = bf[0];
#pragma unroll
        for (int jt = 0; jt < 8; jt++) logit += Pl[t * 8 + jt];
        out[t] = logit;
        out[32 + t] = 1.f / (1.f + expf(-logit));
    }
}

// ---------------------------------------------------------------------------
extern "C" void kernel_launch(void* const* d_in, const int* in_sizes, int n_in,
                              void* d_out, int out_size, void* d_ws, size_t ws_size,
                              hipStream_t stream)
{
    const int*   inputs = (const int*)  d_in[0];
    const float* emb    = (const float*)d_in[1];
    const float* Wp     = (const float*)d_in[2];
    const float* bp     = (const float*)d_in[3];
    const float* Wo     = (const float*)d_in[4];
    const float* bo     = (const float*)d_in[5];
    const float* ln1_g  = (const float*)d_in[6];
    const float* ln1_b  = (const float*)d_in[7];
    const float* W1     = (const float*)d_in[8];
    const float* b1     = (const float*)d_in[9];
    const float* W2     = (const float*)d_in[10];
    const float* b2     = (const float*)d_in[11];
    const float* ln2_g  = (const float*)d_in[12];
    const float* ln2_b  = (const float*)d_in[13];
    const float* Wh     = (const float*)d_in[14];
    const float* bh     = (const float*)d_in[15];
    const float* Wf     = (const float*)d_in[16];
    const float* bf     = (const float*)d_in[17];
    float* out = (float*)d_out;

    char* p = (char*)d_ws;
    float* PE    = (float*)p;  p += 2097152;    // (1024,512)
    float* X0    = (float*)p;  p += 65536;      // (32,512)
    float* r     = (float*)p;  p += 262144;     // (128,512)
    float* alpha = (float*)p;  p += 1024;       // (128)
    float* C0    = (float*)p;  p += 65536;      // (32,512)
    float* Y1    = (float*)p;  p += 65536;      // (32,512)
    float* Tpp   = (float*)p;  p += 2097152;    // (32,8,4,512)
    float* Gp    = (float*)p;  p += 4096;       // (32,8,4)
    float* Hp2p  = (float*)p;  p += 4194304;    // (64,32,512)
    float* Pl    = (float*)p;  p += 1024;       // (32,8)

    void* args[] = {
        (void*)&inputs, (void*)&emb, (void*)&Wp, (void*)&bp, (void*)&Wo,
        (void*)&bo, (void*)&ln1_g, (void*)&ln1_b, (void*)&W1, (void*)&b1,
        (void*)&W2, (void*)&b2, (void*)&ln2_g, (void*)&ln2_b, (void*)&Wh,
        (void*)&bh, (void*)&Wf, (void*)&bf, (void*)&out,
        (void*)&PE, (void*)&X0, (void*)&r, (void*)&alpha, (void*)&C0,
        (void*)&Y1, (void*)&Tpp, (void*)&Gp, (void*)&Hp2p, (void*)&Pl
    };
    hipLaunchCooperativeKernel((void*)mega_k, dim3(256), dim3(512),
                               args, 0, stream);
}